// Round 2
// baseline (8235.641 us; speedup 1.0000x reference)
//
#include <hip/hip_runtime.h>
#include <hip/hip_bf16.h>

typedef __hip_bfloat16 bf16;
typedef unsigned short u16;

#define D_MODEL 1024
#define NUM_HEADS 16
#define DEPTH 64
#define BATCH 4
#define SEQ 1024

// Runtime-dtype load: isbf ? bf16 : fp32
__device__ __forceinline__ float ldDyn(const void* p, size_t i, int isbf) {
  return isbf ? __bfloat162float(((const bf16*)p)[i]) : ((const float*)p)[i];
}

// Detect whether input arrays are bf16 (1) or fp32 (0) by inspecting the low
// 16-bit halves of q's first 64 32-bit words. bf16 N(0,1) data: every half is
// a sane bf16 (exp ~119-129). fp32 data: low halves are random mantissa bits
// (exp uniform over 0..255, ~20% land in [100,150]). Threshold 48 separates.
__global__ void detect_kernel(const u16* __restrict__ q, int* __restrict__ flag) {
  if (threadIdx.x == 0 && blockIdx.x == 0) {
    int sane = 0;
    for (int i = 0; i < 64; ++i) {
      u16 h = q[2 * i];
      int e = (h >> 7) & 0xFF;
      if (e >= 100 && e <= 150) ++sane;
    }
    *flag = (sane >= 48) ? 1 : 0;
  }
}

// C(M,N) = A(M,K) @ W(K,N) + bias(N), fp32 accumulate.
// AMODE: 1 = A is always bf16 (internal intermediate); 0 = A dtype per runtime flag.
// OMODE: 1 = C is always bf16 (internal); 0 = C dtype per runtime flag (final out).
template <int AMODE, int OMODE>
__global__ void gemm_bias_kernel(const void* __restrict__ A, const void* __restrict__ W,
                                 const void* __restrict__ bias, void* __restrict__ C,
                                 int M, int N, int K, const int* __restrict__ flagp) {
  const int isbf = *flagp;
  __shared__ float As[32][33];
  __shared__ float Bs[32][33];
  const int tx = threadIdx.x & 15;
  const int ty = threadIdx.x >> 4;
  const int row0 = blockIdx.y * 32;
  const int col0 = blockIdx.x * 32;
  float acc00 = 0.f, acc01 = 0.f, acc10 = 0.f, acc11 = 0.f;
  for (int k0 = 0; k0 < K; k0 += 32) {
    for (int i = threadIdx.x; i < 1024; i += 256) {
      int r = i >> 5, c = i & 31;
      size_t ai = (size_t)(row0 + r) * K + k0 + c;
      As[r][c] = (AMODE == 1) ? __bfloat162float(((const bf16*)A)[ai]) : ldDyn(A, ai, isbf);
      Bs[r][c] = ldDyn(W, (size_t)(k0 + r) * N + col0 + c, isbf);
    }
    __syncthreads();
#pragma unroll
    for (int kk = 0; kk < 32; ++kk) {
      float a0 = As[ty * 2 + 0][kk];
      float a1 = As[ty * 2 + 1][kk];
      float b0 = Bs[kk][tx * 2 + 0];
      float b1 = Bs[kk][tx * 2 + 1];
      acc00 += a0 * b0; acc01 += a0 * b1;
      acc10 += a1 * b0; acc11 += a1 * b1;
    }
    __syncthreads();
  }
  float bb0 = ldDyn(bias, (size_t)(col0 + tx * 2 + 0), isbf);
  float bb1 = ldDyn(bias, (size_t)(col0 + tx * 2 + 1), isbf);
  size_t r0 = (size_t)(row0 + ty * 2) * N + col0;
  float v00 = acc00 + bb0, v01 = acc01 + bb1, v10 = acc10 + bb0, v11 = acc11 + bb1;
  if (OMODE == 1 || isbf) {
    bf16* Cb = (bf16*)C;
    Cb[r0 + tx * 2 + 0] = __float2bfloat16(v00);
    Cb[r0 + tx * 2 + 1] = __float2bfloat16(v01);
    Cb[r0 + N + tx * 2 + 0] = __float2bfloat16(v10);
    Cb[r0 + N + tx * 2 + 1] = __float2bfloat16(v11);
  } else {
    float* Cf = (float*)C;
    Cf[r0 + tx * 2 + 0] = v00;
    Cf[r0 + tx * 2 + 1] = v01;
    Cf[r0 + N + tx * 2 + 0] = v10;
    Cf[r0 + N + tx * 2 + 1] = v11;
  }
}

// One block (256 threads) per (b, h, q-row). scores = content dot + pos dot with
// theta overrides at q==0 / k==0; softmax; weighted V sum. All tensors bf16.
__global__ void attn_kernel(const bf16* __restrict__ Q, const bf16* __restrict__ Kc,
                            const bf16* __restrict__ V, const bf16* __restrict__ Qp,
                            const bf16* __restrict__ Kp,
                            const void* __restrict__ th_cc, const void* __restrict__ th_co,
                            const void* __restrict__ th_oc, bf16* __restrict__ O,
                            const int* __restrict__ flagp) {
  const int isbf = *flagp;
  const int qi = blockIdx.x;
  const int h = blockIdx.y;
  const int b = blockIdx.z;
  const int t = threadIdx.x;  // 256 threads

  __shared__ float qrow[128];  // [0:64] content, [64:128] pos
  __shared__ float sc[SEQ];
  __shared__ float red[256];

  if (t < 64) {
    qrow[t] = __bfloat162float(Q[((size_t)(b * SEQ + qi)) * D_MODEL + h * DEPTH + t]);
    qrow[64 + t] = __bfloat162float(Qp[(size_t)qi * D_MODEL + h * DEPTH + t]);
  }
  __syncthreads();

  const float tcc = ldDyn(th_cc, h, isbf);
  const float tco = ldDyn(th_co, h, isbf);
  const float toc = ldDyn(th_oc, h, isbf);

  for (int k = t; k < SEQ; k += 256) {
    const bf16* krow = &Kc[((size_t)(b * SEQ + k)) * D_MODEL + h * DEPTH];
    const bf16* kprow = &Kp[(size_t)k * D_MODEL + h * DEPTH];
    float c = 0.f, p = 0.f;
#pragma unroll
    for (int d = 0; d < DEPTH; ++d) {
      c += qrow[d] * __bfloat162float(krow[d]);
      p += qrow[64 + d] * __bfloat162float(kprow[d]);
    }
    if (qi == 0 && k == 0) p = tcc;
    else if (qi == 0) p = tco;
    else if (k == 0) p = toc;
    sc[k] = (c + p) * 0.125f;  // 1/sqrt(64)
  }
  __syncthreads();

  // max reduce
  float m = -INFINITY;
  for (int k = t; k < SEQ; k += 256) m = fmaxf(m, sc[k]);
  red[t] = m;
  __syncthreads();
  for (int s2 = 128; s2 > 0; s2 >>= 1) {
    if (t < s2) red[t] = fmaxf(red[t], red[t + s2]);
    __syncthreads();
  }
  m = red[0];
  __syncthreads();

  // exp + sum
  float sum = 0.f;
  for (int k = t; k < SEQ; k += 256) {
    float e = expf(sc[k] - m);
    sc[k] = e;
    sum += e;
  }
  red[t] = sum;
  __syncthreads();
  for (int s2 = 128; s2 > 0; s2 >>= 1) {
    if (t < s2) red[t] += red[t + s2];
    __syncthreads();
  }
  const float inv = 1.f / red[0];
  __syncthreads();

  // out[d] = sum_k sc[k] * V[k, d]; thread t: d = t&63, k-chunk = t>>6
  const int d = t & 63;
  const int ch = t >> 6;
  float acc = 0.f;
  for (int k = ch * 256; k < ch * 256 + 256; ++k) {
    acc += sc[k] * __bfloat162float(V[((size_t)(b * SEQ + k)) * D_MODEL + h * DEPTH + d]);
  }
  red[t] = acc;
  __syncthreads();
  if (t < 64) {
    float o = (red[t] + red[t + 64] + red[t + 128] + red[t + 192]) * inv;
    O[((size_t)(b * SEQ + qi)) * D_MODEL + h * DEPTH + t] = __float2bfloat16(o);
  }
}

extern "C" void kernel_launch(void* const* d_in, const int* in_sizes, int n_in,
                              void* d_out, int out_size, void* d_ws, size_t ws_size,
                              hipStream_t stream) {
  const void* q = d_in[0];
  const void* k = d_in[1];
  const void* v = d_in[2];
  const void* Wq = d_in[3];
  const void* bq = d_in[4];
  const void* Wk = d_in[5];
  const void* bk = d_in[6];
  const void* Wv = d_in[7];
  const void* bv = d_in[8];
  const void* Uq = d_in[9];
  const void* buq = d_in[10];
  const void* Uk = d_in[11];
  const void* buk = d_in[12];
  const void* pos = d_in[13];  // (MAX_LEN, D_MODEL); first SEQ rows used
  const void* th_cc = d_in[14];
  const void* th_co = d_in[15];
  const void* th_oc = d_in[16];
  const void* Wo = d_in[17];
  const void* bo = d_in[18];

  const int M = BATCH * SEQ;  // 4096
  char* wsb = (char*)d_ws;
  int* flag = (int*)wsb;
  bf16* Qc = (bf16*)(wsb + 256);            // 4096*1024  (8 MB)
  bf16* Kc = Qc + (size_t)M * D_MODEL;      // 8 MB
  bf16* Vc = Kc + (size_t)M * D_MODEL;      // 8 MB
  bf16* Qp = Vc + (size_t)M * D_MODEL;      // 1024*1024 (2 MB)
  bf16* Kp = Qp + (size_t)SEQ * D_MODEL;    // 2 MB
  bf16* AO = Kp + (size_t)SEQ * D_MODEL;    // 8 MB   -> total ~36 MB

  detect_kernel<<<1, 64, 0, stream>>>((const u16*)q, flag);

  dim3 blk(256);
  dim3 gproj(D_MODEL / 32, M / 32);
  gemm_bias_kernel<0, 1><<<gproj, blk, 0, stream>>>(q, Wq, bq, Qc, M, D_MODEL, D_MODEL, flag);
  gemm_bias_kernel<0, 1><<<gproj, blk, 0, stream>>>(k, Wk, bk, Kc, M, D_MODEL, D_MODEL, flag);
  gemm_bias_kernel<0, 1><<<gproj, blk, 0, stream>>>(v, Wv, bv, Vc, M, D_MODEL, D_MODEL, flag);

  dim3 gpos(D_MODEL / 32, SEQ / 32);
  gemm_bias_kernel<0, 1><<<gpos, blk, 0, stream>>>(pos, Uq, buq, Qp, SEQ, D_MODEL, D_MODEL, flag);
  gemm_bias_kernel<0, 1><<<gpos, blk, 0, stream>>>(pos, Uk, buk, Kp, SEQ, D_MODEL, D_MODEL, flag);

  dim3 gattn(SEQ, NUM_HEADS, BATCH);
  attn_kernel<<<gattn, blk, 0, stream>>>(Qc, Kc, Vc, Qp, Kp, th_cc, th_co, th_oc, AO, flag);

  gemm_bias_kernel<1, 0><<<gproj, blk, 0, stream>>>(AO, Wo, bo, d_out, M, D_MODEL, D_MODEL, flag);
}

// Round 3
// 705.658 us; speedup vs baseline: 11.6709x; 11.6709x over previous
//
#include <hip/hip_runtime.h>
#include <hip/hip_bf16.h>

typedef __hip_bfloat16 bf16;
typedef unsigned short u16;
typedef __attribute__((ext_vector_type(8))) short short8;
typedef __attribute__((ext_vector_type(4))) float f32x4;

#define D_MODEL 1024
#define NUM_HEADS 16
#define DEPTH 64
#define BATCH 4
#define SEQ 1024

__device__ __forceinline__ float ldDyn(const void* p, size_t i, int isbf) {
  return isbf ? __bfloat162float(((const bf16*)p)[i]) : ((const float*)p)[i];
}
__device__ __forceinline__ u16 f2bf(float f) {
  bf16 h = __float2bfloat16(f);
  return *(u16*)&h;
}

// Detect input dtype: bf16 (1) vs fp32 (0). See round-1 notes.
__global__ void detect_kernel(const u16* __restrict__ q, int* __restrict__ flag) {
  if (threadIdx.x == 0 && blockIdx.x == 0) {
    int sane = 0;
    for (int i = 0; i < 64; ++i) {
      u16 h = q[2 * i];
      int e = (h >> 7) & 0xFF;
      if (e >= 100 && e <= 150) ++sane;
    }
    *flag = (sane >= 48) ? 1 : 0;
  }
}

// C(M,N) = A(M,K) @ W(K,N) + bias(N). MFMA 16x16x32 bf16, fp32 accumulate.
// Tile 128x128, BK=32, 256 threads = 4 waves in 2x2, each wave 64x64 (4x4 frags).
// AMODE: 1 = A always bf16 (internal); 0 = per runtime flag.
// OMODE: 1 = C always bf16 (internal); 0 = per runtime flag (final out).
template <int AMODE, int OMODE>
__global__ __launch_bounds__(256) void gemm_mfma(const void* __restrict__ A,
                                                 const void* __restrict__ W,
                                                 const void* __restrict__ bias,
                                                 void* __restrict__ C, int M, int N, int K,
                                                 const int* __restrict__ flagp) {
  const int isbf = *flagp;
  __shared__ short As[128][40];   // [m][k] bf16 bits, pad 32->40 (b128 reads, 2-way ok)
  __shared__ short Ws[32][136];   // [k][n] natural, pad 128->136 (u16 col reads, 2-way ok)
  const int t = threadIdx.x;
  const int wave = t >> 6, lane = t & 63;
  const int quad = lane >> 4, c16 = lane & 15;
  const int wrow = wave >> 1, wcol = wave & 1;
  const int row0 = blockIdx.y * 128, col0 = blockIdx.x * 128;

  f32x4 acc[4][4];
#pragma unroll
  for (int mt = 0; mt < 4; ++mt)
#pragma unroll
    for (int nt = 0; nt < 4; ++nt) acc[mt][nt] = {0.f, 0.f, 0.f, 0.f};

  for (int k0 = 0; k0 < K; k0 += 32) {
    // stage A tile 128x32 (512 chunks of 8)
#pragma unroll
    for (int i = 0; i < 2; ++i) {
      int c = t + 256 * i;
      int r = c >> 2, cc = (c & 3) * 8;
      size_t gi = (size_t)(row0 + r) * K + k0 + cc;
      short8 v;
      if (AMODE == 1 || isbf) {
        v = *(const short8*)((const u16*)A + gi);
      } else {
        const float* af = (const float*)A + gi;
#pragma unroll
        for (int j = 0; j < 8; ++j) ((u16*)&v)[j] = f2bf(af[j]);
      }
      *(short8*)&As[r][cc] = v;
    }
    // stage W tile 32x128
#pragma unroll
    for (int i = 0; i < 2; ++i) {
      int c = t + 256 * i;
      int r = c >> 4, cc = (c & 15) * 8;
      size_t gi = (size_t)(k0 + r) * N + col0 + cc;
      short8 v;
      if (isbf) {
        v = *(const short8*)((const u16*)W + gi);
      } else {
        const float* wf = (const float*)W + gi;
#pragma unroll
        for (int j = 0; j < 8; ++j) ((u16*)&v)[j] = f2bf(wf[j]);
      }
      *(short8*)&Ws[r][cc] = v;
    }
    __syncthreads();

    short8 af[4];
#pragma unroll
    for (int mt = 0; mt < 4; ++mt)
      af[mt] = *(const short8*)&As[wrow * 64 + mt * 16 + c16][quad * 8];
#pragma unroll
    for (int nt = 0; nt < 4; ++nt) {
      short8 bfv;
#pragma unroll
      for (int j = 0; j < 8; ++j)
        ((u16*)&bfv)[j] = (u16)Ws[quad * 8 + j][wcol * 64 + nt * 16 + c16];
#pragma unroll
      for (int mt = 0; mt < 4; ++mt)
        acc[mt][nt] = __builtin_amdgcn_mfma_f32_16x16x32_bf16(af[mt], bfv, acc[mt][nt], 0, 0, 0);
    }
    __syncthreads();
  }

#pragma unroll
  for (int nt = 0; nt < 4; ++nt) {
    int gc = col0 + wcol * 64 + nt * 16 + c16;
    float bb = ldDyn(bias, gc, isbf);
#pragma unroll
    for (int mt = 0; mt < 4; ++mt)
#pragma unroll
      for (int r = 0; r < 4; ++r) {
        int gr = row0 + wrow * 64 + mt * 16 + quad * 4 + r;
        float v = acc[mt][nt][r] + bb;
        if (OMODE == 1 || isbf)
          ((bf16*)C)[(size_t)gr * N + gc] = __float2bfloat16(v);
        else
          ((float*)C)[(size_t)gr * N + gc] = v;
      }
  }
}

// Flash attention with augmented 128-dim features [Qc|Qp], [Kc|Kp].
// Block: 256 thr = 4 waves, each wave a 16-row q strip of a 64-row q tile.
// K-loop over 16 tiles of 64 keys. Theta overrides handled by zeroing the
// pos-half of q==0 Q-frags and k==0 K-rows, then adding theta at those spots.
__global__ __launch_bounds__(256) void flash_attn(
    const bf16* __restrict__ Qc, const bf16* __restrict__ Kc, const bf16* __restrict__ Vc,
    const bf16* __restrict__ Qp, const bf16* __restrict__ Kp,
    const void* __restrict__ th_cc, const void* __restrict__ th_co,
    const void* __restrict__ th_oc, bf16* __restrict__ O, const int* __restrict__ flagp) {
  const int isbf = *flagp;
  const int qt = blockIdx.x, h = blockIdx.y, b = blockIdx.z;
  const int t = threadIdx.x, wave = t >> 6, lane = t & 63;
  const int quad = lane >> 4, c16 = lane & 15;

  __shared__ short Kt[64][136];     // [k-row][128 aug dims], pad -> b128 frag reads 2-way
  __shared__ short Vt[64][72];      // [k-row][64 d], natural; u16 col frag reads 2-way
  __shared__ short Pt[4][16][72];   // per-wave P strip [m][k], b128 A-frag reads

  const float tcc = ldDyn(th_cc, h, isbf);
  const float tco = ldDyn(th_co, h, isbf);
  const float toc = ldDyn(th_oc, h, isbf);

  // Preload Q A-frags (loop-invariant): m = c16 row of this wave's strip.
  const int qrow_m = qt * 64 + wave * 16 + c16;
  short8 qf[4];
#pragma unroll
  for (int ks = 0; ks < 4; ++ks) {
    int d = ks * 32 + quad * 8;
    const bf16* src = (d < 64)
        ? Qc + ((size_t)(b * SEQ + qrow_m)) * D_MODEL + h * DEPTH + d
        : Qp + (size_t)qrow_m * D_MODEL + h * DEPTH + (d - 64);
    qf[ks] = *(const short8*)src;
  }
  if (qrow_m == 0) {  // zero pos-half for q==0 (theta_co/theta_cc replace pos there)
    qf[2] = (short8)0;
    qf[3] = (short8)0;
  }

  f32x4 accO[4];
#pragma unroll
  for (int nt = 0; nt < 4; ++nt) accO[nt] = {0.f, 0.f, 0.f, 0.f};
  float mrow[4] = {-1e30f, -1e30f, -1e30f, -1e30f};
  float lrow[4] = {0.f, 0.f, 0.f, 0.f};

  for (int kt = 0; kt < 16; ++kt) {
    __syncthreads();
    // stage K-hat tile 64x128
#pragma unroll
    for (int i = 0; i < 4; ++i) {
      int c = t + 256 * i;
      int r = c >> 4, cc = (c & 15) * 8;
      short8 v;
      if (cc < 64) {
        v = *(const short8*)(Kc + ((size_t)(b * SEQ + kt * 64 + r)) * D_MODEL + h * DEPTH + cc);
      } else if (kt == 0 && r == 0) {
        v = (short8)0;  // zero pos-half of k==0 row (theta_oc/theta_cc replace pos there)
      } else {
        v = *(const short8*)(Kp + ((size_t)(kt * 64 + r)) * D_MODEL + h * DEPTH + (cc - 64));
      }
      *(short8*)&Kt[r][cc] = v;
    }
    // stage V tile 64x64
#pragma unroll
    for (int i = 0; i < 2; ++i) {
      int c = t + 256 * i;
      int kk = c >> 3, dc = (c & 7) * 8;
      *(short8*)&Vt[kk][dc] =
          *(const short8*)(Vc + ((size_t)(b * SEQ + kt * 64 + kk)) * D_MODEL + h * DEPTH + dc);
    }
    __syncthreads();

    // S strip = Q-strip (16x128) x K-tile^T (128x64)
    f32x4 accS[4];
#pragma unroll
    for (int nt = 0; nt < 4; ++nt) accS[nt] = {0.f, 0.f, 0.f, 0.f};
#pragma unroll
    for (int nt = 0; nt < 4; ++nt)
#pragma unroll
      for (int ks = 0; ks < 4; ++ks) {
        short8 kf = *(const short8*)&Kt[nt * 16 + c16][ks * 32 + quad * 8];
        accS[nt] = __builtin_amdgcn_mfma_f32_16x16x32_bf16(qf[ks], kf, accS[nt], 0, 0, 0);
      }

    float s[4][4];
#pragma unroll
    for (int nt = 0; nt < 4; ++nt)
#pragma unroll
      for (int r = 0; r < 4; ++r) s[nt][r] = accS[nt][r] * 0.125f;

    // theta adds at q==0 / k==0 (pos part already zeroed structurally)
    if (kt == 0 || (qt == 0 && wave == 0)) {
#pragma unroll
      for (int nt = 0; nt < 4; ++nt)
#pragma unroll
        for (int r = 0; r < 4; ++r) {
          int kcol = kt * 64 + nt * 16 + c16;
          int qrow = qt * 64 + wave * 16 + quad * 4 + r;
          float add = 0.f;
          if (qrow == 0 && kcol == 0) add = tcc;
          else if (qrow == 0) add = tco;
          else if (kcol == 0) add = toc;
          s[nt][r] += add * 0.125f;
        }
    }

    // online softmax per row (row = quad*4+r; reduce across the 16 c16 lanes)
    float mx[4];
#pragma unroll
    for (int r = 0; r < 4; ++r)
      mx[r] = fmaxf(fmaxf(s[0][r], s[1][r]), fmaxf(s[2][r], s[3][r]));
#pragma unroll
    for (int d = 1; d < 16; d <<= 1)
#pragma unroll
      for (int r = 0; r < 4; ++r) mx[r] = fmaxf(mx[r], __shfl_xor(mx[r], d, 64));

    float al[4];
#pragma unroll
    for (int r = 0; r < 4; ++r) {
      float mn = fmaxf(mrow[r], mx[r]);
      al[r] = __expf(mrow[r] - mn);
      mrow[r] = mn;
    }

    float rs[4] = {0.f, 0.f, 0.f, 0.f};
#pragma unroll
    for (int nt = 0; nt < 4; ++nt)
#pragma unroll
      for (int r = 0; r < 4; ++r) {
        float p = __expf(s[nt][r] - mrow[r]);
        rs[r] += p;
        Pt[wave][quad * 4 + r][nt * 16 + c16] = (short)f2bf(p);
      }
#pragma unroll
    for (int d = 1; d < 16; d <<= 1)
#pragma unroll
      for (int r = 0; r < 4; ++r) rs[r] += __shfl_xor(rs[r], d, 64);
#pragma unroll
    for (int r = 0; r < 4; ++r) lrow[r] = lrow[r] * al[r] + rs[r];
#pragma unroll
    for (int nt = 0; nt < 4; ++nt)
#pragma unroll
      for (int r = 0; r < 4; ++r) accO[nt][r] *= al[r];

    // O strip += P strip (16x64) x V tile (64x64); P via LDS C->A layout roundtrip
#pragma unroll
    for (int ks = 0; ks < 2; ++ks) {
      short8 pf = *(const short8*)&Pt[wave][c16][ks * 32 + quad * 8];
#pragma unroll
      for (int nt = 0; nt < 4; ++nt) {
        short8 vb;
#pragma unroll
        for (int j = 0; j < 8; ++j)
          ((u16*)&vb)[j] = (u16)Vt[ks * 32 + quad * 8 + j][nt * 16 + c16];
        accO[nt] = __builtin_amdgcn_mfma_f32_16x16x32_bf16(pf, vb, accO[nt], 0, 0, 0);
      }
    }
  }

#pragma unroll
  for (int nt = 0; nt < 4; ++nt)
#pragma unroll
    for (int r = 0; r < 4; ++r) {
      int qrow = qt * 64 + wave * 16 + quad * 4 + r;
      float o = accO[nt][r] / lrow[r];
      O[((size_t)(b * SEQ + qrow)) * D_MODEL + h * DEPTH + nt * 16 + c16] = __float2bfloat16(o);
    }
}

extern "C" void kernel_launch(void* const* d_in, const int* in_sizes, int n_in,
                              void* d_out, int out_size, void* d_ws, size_t ws_size,
                              hipStream_t stream) {
  const void* q = d_in[0];
  const void* k = d_in[1];
  const void* v = d_in[2];
  const void* Wq = d_in[3];
  const void* bq = d_in[4];
  const void* Wk = d_in[5];
  const void* bk = d_in[6];
  const void* Wv = d_in[7];
  const void* bv = d_in[8];
  const void* Uq = d_in[9];
  const void* buq = d_in[10];
  const void* Uk = d_in[11];
  const void* buk = d_in[12];
  const void* pos = d_in[13];
  const void* th_cc = d_in[14];
  const void* th_co = d_in[15];
  const void* th_oc = d_in[16];
  const void* Wo = d_in[17];
  const void* bo = d_in[18];

  const int M = BATCH * SEQ;  // 4096
  char* wsb = (char*)d_ws;
  int* flag = (int*)wsb;
  bf16* Qc = (bf16*)(wsb + 256);
  bf16* Kc = Qc + (size_t)M * D_MODEL;
  bf16* Vc = Kc + (size_t)M * D_MODEL;
  bf16* Qp = Vc + (size_t)M * D_MODEL;
  bf16* Kp = Qp + (size_t)SEQ * D_MODEL;
  bf16* AO = Kp + (size_t)SEQ * D_MODEL;  // total ~36 MB

  detect_kernel<<<1, 64, 0, stream>>>((const u16*)q, flag);

  dim3 blk(256);
  dim3 gproj(D_MODEL / 128, M / 128);   // (8, 32)
  dim3 gpos(D_MODEL / 128, SEQ / 128);  // (8, 8)
  gemm_mfma<0, 1><<<gproj, blk, 0, stream>>>(q, Wq, bq, Qc, M, D_MODEL, D_MODEL, flag);
  gemm_mfma<0, 1><<<gproj, blk, 0, stream>>>(k, Wk, bk, Kc, M, D_MODEL, D_MODEL, flag);
  gemm_mfma<0, 1><<<gproj, blk, 0, stream>>>(v, Wv, bv, Vc, M, D_MODEL, D_MODEL, flag);
  gemm_mfma<0, 1><<<gpos, blk, 0, stream>>>(pos, Uq, buq, Qp, SEQ, D_MODEL, D_MODEL, flag);
  gemm_mfma<0, 1><<<gpos, blk, 0, stream>>>(pos, Uk, buk, Kp, SEQ, D_MODEL, D_MODEL, flag);

  dim3 gattn(SEQ / 64, NUM_HEADS, BATCH);  // (16, 16, 4)
  flash_attn<<<gattn, blk, 0, stream>>>(Qc, Kc, Vc, Qp, Kp, th_cc, th_co, th_oc, AO, flag);

  gemm_mfma<1, 0><<<gproj, blk, 0, stream>>>(AO, Wo, bo, d_out, M, D_MODEL, D_MODEL, flag);
}

// Round 4
// 410.333 us; speedup vs baseline: 20.0706x; 1.7197x over previous
//
#include <hip/hip_runtime.h>
#include <hip/hip_bf16.h>

typedef __hip_bfloat16 bf16;
typedef unsigned short u16;
typedef __attribute__((ext_vector_type(8))) short short8;
typedef __attribute__((ext_vector_type(4))) short short4v;
typedef __attribute__((ext_vector_type(4))) float f32x4;

#define D_MODEL 1024
#define NUM_HEADS 16
#define DEPTH 64
#define BATCH 4
#define SEQ 1024

__device__ __forceinline__ float ldDyn(const void* p, size_t i, int isbf) {
  return isbf ? __bfloat162float(((const bf16*)p)[i]) : ((const float*)p)[i];
}
__device__ __forceinline__ u16 f2bf(float f) {
  bf16 h = __float2bfloat16(f);
  return *(u16*)&h;
}

// Detect input dtype: bf16 (1) vs fp32 (0). See round-1 notes.
__global__ void detect_kernel(const u16* __restrict__ q, int* __restrict__ flag) {
  if (threadIdx.x == 0 && blockIdx.x == 0) {
    int sane = 0;
    for (int i = 0; i < 64; ++i) {
      u16 h = q[2 * i];
      int e = (h >> 7) & 0xFF;
      if (e >= 100 && e <= 150) ++sane;
    }
    *flag = (sane >= 48) ? 1 : 0;
  }
}

// Batched 1024x1024 transpose (+convert to bf16): out[z][n][k] = in[z][k][n].
__global__ __launch_bounds__(256) void transpose_w(
    const void* W0, const void* W1, const void* W2, const void* W3, const void* W4,
    const void* W5, u16* __restrict__ WT, const int* __restrict__ flagp) {
  const int isbf = *flagp;
  const int z = blockIdx.z;
  const void* W = (z == 0) ? W0 : (z == 1) ? W1 : (z == 2) ? W2
                 : (z == 3) ? W3 : (z == 4) ? W4 : W5;
  u16* out = WT + (size_t)z * D_MODEL * D_MODEL;
  __shared__ u16 tile[32][33];
  const int t = threadIdx.x;
  const int tx = t & 31, ty = t >> 5;  // 8 rows per pass
  const int r0 = blockIdx.y * 32, c0 = blockIdx.x * 32;
#pragma unroll
  for (int i = 0; i < 4; ++i) {
    size_t gi = (size_t)(r0 + ty + 8 * i) * D_MODEL + c0 + tx;
    tile[ty + 8 * i][tx] = isbf ? ((const u16*)W)[gi] : f2bf(((const float*)W)[gi]);
  }
  __syncthreads();
#pragma unroll
  for (int i = 0; i < 4; ++i)
    out[(size_t)(c0 + ty + 8 * i) * D_MODEL + r0 + tx] = tile[tx][ty + 8 * i];
}

// C(M,N) = A(M,K) @ W(K,N) + bias(N), where WT = W^T (N x K, bf16) is passed.
// MFMA 16x16x32 bf16, 128x128 tile, BK=32, 4 waves 2x2, 4x4 frags each.
// All LDS tiles XOR-swizzled (16B chunk index ^ row) -> all b128, ~2-way max.
// AMODE: 1 = A always bf16; 0 = A per runtime flag.
// omode: 0 = final out (dtype per flag, natural); 1 = bf16 natural; 2 = bf16 transposed [N][M].
template <int AMODE>
__global__ __launch_bounds__(256) void gemm_mfma(
    const void* A0, const void* A1, const void* A2,
    const u16* W0, const u16* W1, const u16* W2,
    const void* b0, const void* b1, const void* b2,
    void* C0, void* C1, void* C2,
    int M, int N, int K, int om0, int om1, int om2, const int* __restrict__ flagp) {
  const int isbf = *flagp;
  const int z = blockIdx.z;
  const void* A = (z == 0) ? A0 : (z == 1) ? A1 : A2;
  const u16* WT = (z == 0) ? W0 : (z == 1) ? W1 : W2;
  const void* bias = (z == 0) ? b0 : (z == 1) ? b1 : b2;
  void* C = (z == 0) ? C0 : (z == 1) ? C1 : C2;
  const int omode = (z == 0) ? om0 : (z == 1) ? om1 : om2;

  __shared__ short As[128][32];
  __shared__ short Bs[128][32];
  const int t = threadIdx.x;
  const int wave = t >> 6, lane = t & 63;
  const int quad = lane >> 4, c16 = lane & 15;
  const int wrow = wave >> 1, wcol = wave & 1;
  const int row0 = blockIdx.y * 128, col0 = blockIdx.x * 128;

  f32x4 acc[4][4];
#pragma unroll
  for (int mt = 0; mt < 4; ++mt)
#pragma unroll
    for (int nt = 0; nt < 4; ++nt) acc[mt][nt] = {0.f, 0.f, 0.f, 0.f};

  for (int k0 = 0; k0 < K; k0 += 32) {
#pragma unroll
    for (int i = 0; i < 2; ++i) {
      int c = t + 256 * i;
      int r = c >> 2, kc = c & 3;
      size_t gi = (size_t)(row0 + r) * K + k0 + kc * 8;
      short8 v;
      if (AMODE == 1 || isbf) {
        v = *(const short8*)((const u16*)A + gi);
      } else {
        const float* af = (const float*)A + gi;
        float4 lo = *(const float4*)af;
        float4 hi = *(const float4*)(af + 4);
        u16* pv = (u16*)&v;
        pv[0] = f2bf(lo.x); pv[1] = f2bf(lo.y); pv[2] = f2bf(lo.z); pv[3] = f2bf(lo.w);
        pv[4] = f2bf(hi.x); pv[5] = f2bf(hi.y); pv[6] = f2bf(hi.z); pv[7] = f2bf(hi.w);
      }
      *(short8*)&As[r][((kc ^ (r & 3)) * 8)] = v;
      // WT tile: rows are n, contiguous k
      size_t wg = (size_t)(col0 + r) * K + k0 + kc * 8;
      *(short8*)&Bs[r][((kc ^ (r & 3)) * 8)] = *(const short8*)(WT + wg);
    }
    __syncthreads();

    short8 af[4], bfv[4];
#pragma unroll
    for (int mt = 0; mt < 4; ++mt)
      af[mt] = *(const short8*)&As[wrow * 64 + mt * 16 + c16][((quad ^ (c16 & 3)) * 8)];
#pragma unroll
    for (int nt = 0; nt < 4; ++nt)
      bfv[nt] = *(const short8*)&Bs[wcol * 64 + nt * 16 + c16][((quad ^ (c16 & 3)) * 8)];
#pragma unroll
    for (int nt = 0; nt < 4; ++nt)
#pragma unroll
      for (int mt = 0; mt < 4; ++mt)
        acc[mt][nt] = __builtin_amdgcn_mfma_f32_16x16x32_bf16(af[mt], bfv[nt], acc[mt][nt], 0, 0, 0);
    __syncthreads();
  }

#pragma unroll
  for (int nt = 0; nt < 4; ++nt) {
    int gc = col0 + wcol * 64 + nt * 16 + c16;
    float bb = ldDyn(bias, gc, isbf);
#pragma unroll
    for (int mt = 0; mt < 4; ++mt) {
      int gr0 = row0 + wrow * 64 + mt * 16 + quad * 4;
      if (omode == 2) {  // transposed store: C^T[n][m], contiguous 4 along m
        short4v pk;
#pragma unroll
        for (int r = 0; r < 4; ++r) pk[r] = (short)f2bf(acc[mt][nt][r] + bb);
        *(short4v*)&((u16*)C)[(size_t)gc * M + gr0] = pk;
      } else if (omode == 1 || isbf) {
#pragma unroll
        for (int r = 0; r < 4; ++r)
          ((bf16*)C)[(size_t)(gr0 + r) * N + gc] = __float2bfloat16(acc[mt][nt][r] + bb);
      } else {
#pragma unroll
        for (int r = 0; r < 4; ++r)
          ((float*)C)[(size_t)(gr0 + r) * N + gc] = acc[mt][nt][r] + bb;
      }
    }
  }
}

// Flash attention, augmented 128-dim features [Qc|Qp],[Kc|Kp]; V passed transposed
// (VcT[d_model][B*SEQ]). All LDS frag traffic is swizzled b128.
__global__ __launch_bounds__(256) void flash_attn(
    const bf16* __restrict__ Qc, const bf16* __restrict__ Kc, const bf16* __restrict__ VcT,
    const bf16* __restrict__ Qp, const bf16* __restrict__ Kp,
    const void* __restrict__ th_cc, const void* __restrict__ th_co,
    const void* __restrict__ th_oc, bf16* __restrict__ O, const int* __restrict__ flagp) {
  const int isbf = *flagp;
  const int qt = blockIdx.x, h = blockIdx.y, b = blockIdx.z;
  const int t = threadIdx.x, wave = t >> 6, lane = t & 63;
  const int quad = lane >> 4, c16 = lane & 15;

  __shared__ short Kt[64][128];    // [key][128 aug dims], 16B chunks swizzled ^ (key&15)
  __shared__ short Vt[64][64];     // [d][64 keys], chunks swizzled ^ (d&7)
  __shared__ short Pt[4][16][64];  // per-wave P strip [m][k], chunks swizzled ^ (m&7)

  const float tcc = ldDyn(th_cc, h, isbf);
  const float tco = ldDyn(th_co, h, isbf);
  const float toc = ldDyn(th_oc, h, isbf);

  const int qrow_m = qt * 64 + wave * 16 + c16;
  short8 qf[4];
#pragma unroll
  for (int ks = 0; ks < 4; ++ks) {
    int d = ks * 32 + quad * 8;
    const bf16* src = (d < 64)
        ? Qc + ((size_t)(b * SEQ + qrow_m)) * D_MODEL + h * DEPTH + d
        : Qp + (size_t)qrow_m * D_MODEL + h * DEPTH + (d - 64);
    qf[ks] = *(const short8*)src;
  }
  if (qrow_m == 0) {  // zero pos-half for q==0 (theta replaces pos there)
    qf[2] = (short8)0;
    qf[3] = (short8)0;
  }

  f32x4 accO[4];
#pragma unroll
  for (int nt = 0; nt < 4; ++nt) accO[nt] = {0.f, 0.f, 0.f, 0.f};
  float mrow[4] = {-1e30f, -1e30f, -1e30f, -1e30f};
  float lrow[4] = {0.f, 0.f, 0.f, 0.f};

  for (int kt = 0; kt < 16; ++kt) {
    __syncthreads();
    // stage K-hat 64x128 (swizzled)
#pragma unroll
    for (int i = 0; i < 4; ++i) {
      int c = t + 256 * i;
      int r = c >> 4, kc = c & 15;
      short8 v;
      if (kc < 8) {
        v = *(const short8*)(Kc + ((size_t)(b * SEQ + kt * 64 + r)) * D_MODEL + h * DEPTH + kc * 8);
      } else if (kt == 0 && r == 0) {
        v = (short8)0;  // zero pos-half of k==0 row
      } else {
        v = *(const short8*)(Kp + ((size_t)(kt * 64 + r)) * D_MODEL + h * DEPTH + kc * 8 - 64);
      }
      *(short8*)&Kt[r][((kc ^ (r & 15)) * 8)] = v;
    }
    // stage V^T 64(d) x 64(k) (swizzled)
#pragma unroll
    for (int i = 0; i < 2; ++i) {
      int c = t + 256 * i;
      int r = c >> 3, kc = c & 7;
      short8 v = *(const short8*)(VcT + (size_t)(h * DEPTH + r) * (BATCH * SEQ) +
                                  b * SEQ + kt * 64 + kc * 8);
      *(short8*)&Vt[r][((kc ^ (r & 7)) * 8)] = v;
    }
    __syncthreads();

    // S strip = Q-strip (16x128) x K-tile^T
    f32x4 accS[4];
#pragma unroll
    for (int nt = 0; nt < 4; ++nt) accS[nt] = {0.f, 0.f, 0.f, 0.f};
#pragma unroll
    for (int nt = 0; nt < 4; ++nt)
#pragma unroll
      for (int ks = 0; ks < 4; ++ks) {
        short8 kf = *(const short8*)&Kt[nt * 16 + c16][(((ks * 4 + quad) ^ c16) & 15) * 8];
        accS[nt] = __builtin_amdgcn_mfma_f32_16x16x32_bf16(qf[ks], kf, accS[nt], 0, 0, 0);
      }

    float s[4][4];
#pragma unroll
    for (int nt = 0; nt < 4; ++nt)
#pragma unroll
      for (int r = 0; r < 4; ++r) s[nt][r] = accS[nt][r] * 0.125f;

    if (kt == 0 || (qt == 0 && wave == 0)) {
#pragma unroll
      for (int nt = 0; nt < 4; ++nt)
#pragma unroll
        for (int r = 0; r < 4; ++r) {
          int kcol = kt * 64 + nt * 16 + c16;
          int qrow = qt * 64 + wave * 16 + quad * 4 + r;
          float add = 0.f;
          if (qrow == 0 && kcol == 0) add = tcc;
          else if (qrow == 0) add = tco;
          else if (kcol == 0) add = toc;
          s[nt][r] += add * 0.125f;
        }
    }

    // online softmax per row (reduce across 16 c16 lanes)
    float mx[4];
#pragma unroll
    for (int r = 0; r < 4; ++r)
      mx[r] = fmaxf(fmaxf(s[0][r], s[1][r]), fmaxf(s[2][r], s[3][r]));
#pragma unroll
    for (int d = 1; d < 16; d <<= 1)
#pragma unroll
      for (int r = 0; r < 4; ++r) mx[r] = fmaxf(mx[r], __shfl_xor(mx[r], d, 64));

    float al[4];
#pragma unroll
    for (int r = 0; r < 4; ++r) {
      float mn = fmaxf(mrow[r], mx[r]);
      al[r] = __expf(mrow[r] - mn);
      mrow[r] = mn;
    }

    float rs[4] = {0.f, 0.f, 0.f, 0.f};
#pragma unroll
    for (int nt = 0; nt < 4; ++nt)
#pragma unroll
      for (int r = 0; r < 4; ++r) {
        float p = __expf(s[nt][r] - mrow[r]);
        rs[r] += p;
        int row = quad * 4 + r;
        int ch = nt * 2 + (c16 >> 3);
        Pt[wave][row][((ch ^ (row & 7)) * 8) + (c16 & 7)] = (short)f2bf(p);
      }
#pragma unroll
    for (int d = 1; d < 16; d <<= 1)
#pragma unroll
      for (int r = 0; r < 4; ++r) rs[r] += __shfl_xor(rs[r], d, 64);
#pragma unroll
    for (int r = 0; r < 4; ++r) lrow[r] = lrow[r] * al[r] + rs[r];
#pragma unroll
    for (int nt = 0; nt < 4; ++nt)
#pragma unroll
      for (int r = 0; r < 4; ++r) accO[nt][r] *= al[r];

    // O strip += P (16x64) x V (64x64); P C->A via swizzled LDS, V via b128
#pragma unroll
    for (int ks = 0; ks < 2; ++ks) {
      short8 pf = *(const short8*)&Pt[wave][c16][(((ks * 4 + quad) ^ (c16 & 7)) & 7) * 8];
#pragma unroll
      for (int nt = 0; nt < 4; ++nt) {
        short8 vb = *(const short8*)&Vt[nt * 16 + c16][(((ks * 4 + quad) ^ (c16 & 7)) & 7) * 8];
        accO[nt] = __builtin_amdgcn_mfma_f32_16x16x32_bf16(pf, vb, accO[nt], 0, 0, 0);
      }
    }
  }

#pragma unroll
  for (int nt = 0; nt < 4; ++nt)
#pragma unroll
    for (int r = 0; r < 4; ++r) {
      int qrow = qt * 64 + wave * 16 + quad * 4 + r;
      float o = accO[nt][r] / lrow[r];
      O[((size_t)(b * SEQ + qrow)) * D_MODEL + h * DEPTH + nt * 16 + c16] = __float2bfloat16(o);
    }
}

extern "C" void kernel_launch(void* const* d_in, const int* in_sizes, int n_in,
                              void* d_out, int out_size, void* d_ws, size_t ws_size,
                              hipStream_t stream) {
  const void* q = d_in[0];
  const void* k = d_in[1];
  const void* v = d_in[2];
  const void* Wq = d_in[3];
  const void* bq = d_in[4];
  const void* Wk = d_in[5];
  const void* bk = d_in[6];
  const void* Wv = d_in[7];
  const void* bv = d_in[8];
  const void* Uq = d_in[9];
  const void* buq = d_in[10];
  const void* Uk = d_in[11];
  const void* buk = d_in[12];
  const void* pos = d_in[13];
  const void* th_cc = d_in[14];
  const void* th_co = d_in[15];
  const void* th_oc = d_in[16];
  const void* Wo = d_in[17];
  const void* bo = d_in[18];

  const int M = BATCH * SEQ;  // 4096
  const size_t DD = (size_t)D_MODEL * D_MODEL;  // 1M elems
  char* wsb = (char*)d_ws;
  int* flag = (int*)wsb;
  bf16* Qc = (bf16*)(wsb + 256);            // 8 MB
  bf16* Kc = Qc + (size_t)M * D_MODEL;      // 8 MB
  bf16* VcT = Kc + (size_t)M * D_MODEL;     // 8 MB, stored [D_MODEL][M]
  bf16* Qp = VcT + (size_t)M * D_MODEL;     // 2 MB
  bf16* Kp = Qp + (size_t)SEQ * D_MODEL;    // 2 MB
  u16* WT = (u16*)(Kp + (size_t)SEQ * D_MODEL);  // 6 x 2 MB (WqT,WkT,WvT,UqT,UkT,WoT)
  bf16* AO = (bf16*)WT;  // aliases WqT..UqT (dead by flash time); WoT (slot 5) untouched

  detect_kernel<<<1, 64, 0, stream>>>((const u16*)q, flag);

  dim3 blk(256);
  transpose_w<<<dim3(32, 32, 6), blk, 0, stream>>>(Wq, Wk, Wv, Uq, Uk, Wo, WT, flag);

  // q/k/v projections in one launch; Vc written transposed
  gemm_mfma<0><<<dim3(8, 32, 3), blk, 0, stream>>>(
      q, k, v, WT + 0 * DD, WT + 1 * DD, WT + 2 * DD, bq, bk, bv, Qc, Kc, VcT,
      M, D_MODEL, D_MODEL, 1, 1, 2, flag);
  // pos projections
  gemm_mfma<0><<<dim3(8, 8, 2), blk, 0, stream>>>(
      pos, pos, pos, WT + 3 * DD, WT + 4 * DD, WT + 4 * DD, buq, buk, buk, Qp, Kp, Kp,
      SEQ, D_MODEL, D_MODEL, 1, 1, 1, flag);

  flash_attn<<<dim3(SEQ / 64, NUM_HEADS, BATCH), blk, 0, stream>>>(
      Qc, Kc, VcT, Qp, Kp, th_cc, th_co, th_oc, AO, flag);

  gemm_mfma<1><<<dim3(8, 32, 1), blk, 0, stream>>>(
      AO, AO, AO, WT + 5 * DD, WT + 5 * DD, WT + 5 * DD, bo, bo, bo, d_out, d_out, d_out,
      M, D_MODEL, D_MODEL, 0, 0, 0, flag);
}

// Round 5
// 359.607 us; speedup vs baseline: 22.9018x; 1.1411x over previous
//
#include <hip/hip_runtime.h>
#include <hip/hip_bf16.h>

typedef __hip_bfloat16 bf16;
typedef unsigned short u16;
typedef __attribute__((ext_vector_type(8))) short short8;
typedef __attribute__((ext_vector_type(4))) float f32x4;

#define D_MODEL 1024
#define NUM_HEADS 16
#define DEPTH 64
#define BATCH 4
#define SEQ 1024
#define BS (BATCH * SEQ)

__device__ __forceinline__ float ldDyn(const void* p, size_t i, int isbf) {
  return isbf ? __bfloat162float(((const bf16*)p)[i]) : ((const float*)p)[i];
}
__device__ __forceinline__ u16 f2bf(float f) {
  bf16 h = __float2bfloat16(f);
  return *(u16*)&h;
}
// async global->LDS, 16B per lane; LDS dest = wave-uniform base + lane*16
__device__ __forceinline__ void gl2lds16(const void* g, void* l) {
  __builtin_amdgcn_global_load_lds((const __attribute__((address_space(1))) unsigned int*)g,
                                   (__attribute__((address_space(3))) unsigned int*)l, 16, 0, 0);
}

// Detect input dtype: bf16 (1) vs fp32 (0). See round-1 notes.
__global__ void detect_kernel(const u16* __restrict__ q, int* __restrict__ flag) {
  if (threadIdx.x == 0 && blockIdx.x == 0) {
    int sane = 0;
    for (int i = 0; i < 64; ++i) {
      u16 h = q[2 * i];
      int e = (h >> 7) & 0xFF;
      if (e >= 100 && e <= 150) ++sane;
    }
    *flag = (sane >= 48) ? 1 : 0;
  }
}

// Batched 1024x1024 transpose (+convert to bf16): out[z][n][k] = in[z][k][n].
__global__ __launch_bounds__(256) void transpose_w(
    const void* W0, const void* W1, const void* W2, const void* W3, const void* W4,
    const void* W5, u16* __restrict__ WT, const int* __restrict__ flagp) {
  const int isbf = *flagp;
  const int z = blockIdx.z;
  const void* W = (z == 0) ? W0 : (z == 1) ? W1 : (z == 2) ? W2
                 : (z == 3) ? W3 : (z == 4) ? W4 : W5;
  u16* out = WT + (size_t)z * D_MODEL * D_MODEL;
  __shared__ u16 tile[32][33];
  const int t = threadIdx.x;
  const int tx = t & 31, ty = t >> 5;
  const int r0 = blockIdx.y * 32, c0 = blockIdx.x * 32;
#pragma unroll
  for (int i = 0; i < 4; ++i) {
    size_t gi = (size_t)(r0 + ty + 8 * i) * D_MODEL + c0 + tx;
    tile[ty + 8 * i][tx] = isbf ? ((const u16*)W)[gi] : f2bf(((const float*)W)[gi]);
  }
  __syncthreads();
#pragma unroll
  for (int i = 0; i < 4; ++i)
    out[(size_t)(c0 + ty + 8 * i) * D_MODEL + r0 + tx] = tile[tx][ty + 8 * i];
}

struct GArgs {
  const void* A[5];
  const u16* W[5];
  const void* bias[5];
  void* C[5];
  int Mr[5];
  int om[5];
};

// C(M,1024) = A(M,1024) @ W + bias, W passed transposed (WT, bf16).
// m97 structure: global_load_lds(16B) staging, swizzle folded into global index.
// omode: 0 = final out (dtype per flag); 1 = bf16; 2 = bf16 transposed [N][M].
template <int AMODE>
__global__ __launch_bounds__(256) void gemm_mfma(GArgs ga, const int* __restrict__ flagp) {
  const int isbf = *flagp;
  const int z = blockIdx.z;
  const int M = ga.Mr[z];
  const int row0 = blockIdx.y * 128, col0 = blockIdx.x * 128;
  if (row0 >= M) return;
  const void* A = ga.A[z];
  const u16* WT = ga.W[z];
  const void* bias = ga.bias[z];
  void* C = ga.C[z];
  const int omode = ga.om[z];

  __shared__ short As[128][32];
  __shared__ short Bs[128][32];
  const int t = threadIdx.x;
  const int wave = t >> 6, lane = t & 63;
  const int quad = lane >> 4, c16 = lane & 15;
  const int wrow = wave >> 1, wcol = wave & 1;

  f32x4 acc[4][4];
#pragma unroll
  for (int mt = 0; mt < 4; ++mt)
#pragma unroll
    for (int nt = 0; nt < 4; ++nt) acc[mt][nt] = {0.f, 0.f, 0.f, 0.f};

  const bool abf = (AMODE == 1) || isbf;
  for (int k0 = 0; k0 < 1024; k0 += 32) {
    if (abf) {
#pragma unroll
      for (int i = 0; i < 2; ++i) {
        int L = t + 256 * i;
        int r = L >> 2;
        int kc = (L & 3) ^ (r & 3);  // swizzle on the global side; LDS dest stays linear
        gl2lds16((const u16*)A + (size_t)(row0 + r) * 1024 + k0 + kc * 8,
                 (char*)&As[0][0] + (size_t)(i * 256 + wave * 64) * 16);
        gl2lds16(WT + (size_t)(col0 + r) * 1024 + k0 + kc * 8,
                 (char*)&Bs[0][0] + (size_t)(i * 256 + wave * 64) * 16);
      }
    } else {
#pragma unroll
      for (int i = 0; i < 2; ++i) {
        int L = t + 256 * i;
        int r = L >> 2, kc = L & 3;
        const float* af = (const float*)A + (size_t)(row0 + r) * 1024 + k0 + kc * 8;
        float4 lo = *(const float4*)af;
        float4 hi = *(const float4*)(af + 4);
        short8 v;
        u16* pv = (u16*)&v;
        pv[0] = f2bf(lo.x); pv[1] = f2bf(lo.y); pv[2] = f2bf(lo.z); pv[3] = f2bf(lo.w);
        pv[4] = f2bf(hi.x); pv[5] = f2bf(hi.y); pv[6] = f2bf(hi.z); pv[7] = f2bf(hi.w);
        *(short8*)&As[r][((kc ^ (r & 3)) * 8)] = v;
        *(short8*)&Bs[r][((kc ^ (r & 3)) * 8)] =
            *(const short8*)(WT + (size_t)(col0 + r) * 1024 + k0 + kc * 8);
      }
    }
    __syncthreads();

    short8 af[4], bfv[4];
#pragma unroll
    for (int mt = 0; mt < 4; ++mt)
      af[mt] = *(const short8*)&As[wrow * 64 + mt * 16 + c16][((quad ^ (c16 & 3)) * 8)];
#pragma unroll
    for (int nt = 0; nt < 4; ++nt)
      bfv[nt] = *(const short8*)&Bs[wcol * 64 + nt * 16 + c16][((quad ^ (c16 & 3)) * 8)];
#pragma unroll
    for (int nt = 0; nt < 4; ++nt)
#pragma unroll
      for (int mt = 0; mt < 4; ++mt)
        acc[mt][nt] = __builtin_amdgcn_mfma_f32_16x16x32_bf16(af[mt], bfv[nt], acc[mt][nt], 0, 0, 0);
    __syncthreads();
  }

#pragma unroll
  for (int nt = 0; nt < 4; ++nt) {
    int gc = col0 + wcol * 64 + nt * 16 + c16;
    float bb = ldDyn(bias, gc, isbf);
#pragma unroll
    for (int mt = 0; mt < 4; ++mt) {
      int gr0 = row0 + wrow * 64 + mt * 16 + quad * 4;
      if (omode == 2) {
        __attribute__((ext_vector_type(4))) short pk;
#pragma unroll
        for (int r = 0; r < 4; ++r) pk[r] = (short)f2bf(acc[mt][nt][r] + bb);
        *(__attribute__((ext_vector_type(4))) short*)&((u16*)C)[(size_t)gc * M + gr0] = pk;
      } else if (omode == 1 || isbf) {
#pragma unroll
        for (int r = 0; r < 4; ++r)
          ((bf16*)C)[(size_t)(gr0 + r) * 1024 + gc] = __float2bfloat16(acc[mt][nt][r] + bb);
      } else {
#pragma unroll
        for (int r = 0; r < 4; ++r)
          ((float*)C)[(size_t)(gr0 + r) * 1024 + gc] = acc[mt][nt][r] + bb;
      }
    }
  }
}

// Barrier-free flash attention. q-tile 128 (4 waves x 2 strips of 16), 64-key
// tiles. K/V MFMA fragments loaded directly global->register (frag layout is
// contiguous 16B in Kc/Kp/VcT). Q frags register-resident. Only P does an LDS
// roundtrip (per-wave region -> no __syncthreads anywhere).
__global__ __launch_bounds__(256) void flash_attn(
    const bf16* __restrict__ Qc, const bf16* __restrict__ Kc, const bf16* __restrict__ VcT,
    const bf16* __restrict__ Qp, const bf16* __restrict__ Kp,
    const void* __restrict__ th_cc, const void* __restrict__ th_co,
    const void* __restrict__ th_oc, bf16* __restrict__ O, const int* __restrict__ flagp) {
  const int isbf = *flagp;
  const int qt = blockIdx.x, h = blockIdx.y, b = blockIdx.z;
  const int t = threadIdx.x, wave = t >> 6, lane = t & 63;
  const int quad = lane >> 4, c16 = lane & 15;

  __shared__ short Pt[4][32][64];  // per-wave P strips, 16B chunks swizzled ^ (row&7)

  const float tcc = ldDyn(th_cc, h, isbf);
  const float tco = ldDyn(th_co, h, isbf);
  const float toc = ldDyn(th_oc, h, isbf);

  const bf16* kcb = Kc + (size_t)b * SEQ * 1024 + h * 64;
  const bf16* kpb = Kp + h * 64;
  const bf16* vtb = VcT + (size_t)(h * 64) * BS + (size_t)b * SEQ;

  // Q A-frags (register-resident): qf[mt][ks], m-row = c16 of strip mt
  short8 qf[2][4];
#pragma unroll
  for (int mt = 0; mt < 2; ++mt) {
    int qrow = qt * 128 + wave * 32 + mt * 16 + c16;
#pragma unroll
    for (int ks = 0; ks < 4; ++ks) {
      int d = ks * 32 + quad * 8;
      const bf16* src = (d < 64) ? Qc + ((size_t)(b * SEQ + qrow)) * 1024 + h * 64 + d
                                 : Qp + (size_t)qrow * 1024 + h * 64 + (d - 64);
      qf[mt][ks] = *(const short8*)src;
    }
    if (qrow == 0) {  // zero pos-half for q==0 (theta replaces pos there)
      qf[mt][2] = (short8)0;
      qf[mt][3] = (short8)0;
    }
  }

  f32x4 accO[2][4];
#pragma unroll
  for (int mt = 0; mt < 2; ++mt)
#pragma unroll
    for (int nt = 0; nt < 4; ++nt) accO[mt][nt] = {0.f, 0.f, 0.f, 0.f};
  float mrow[2][4], lrow[2][4];
#pragma unroll
  for (int mt = 0; mt < 2; ++mt)
#pragma unroll
    for (int r = 0; r < 4; ++r) { mrow[mt][r] = -1e30f; lrow[mt][r] = 0.f; }

  for (int kt = 0; kt < 16; ++kt) {
    // ---- S = Q-hat (32x128) x K-hat^T, K-frags straight from global ----
    f32x4 accS[2][4];
#pragma unroll
    for (int mt = 0; mt < 2; ++mt)
#pragma unroll
      for (int nt = 0; nt < 4; ++nt) accS[mt][nt] = {0.f, 0.f, 0.f, 0.f};
#pragma unroll
    for (int nt = 0; nt < 4; ++nt) {
      const int key = kt * 64 + nt * 16 + c16;
#pragma unroll
      for (int ks = 0; ks < 4; ++ks) {
        short8 kfv;
        if (ks < 2) {
          kfv = *(const short8*)(kcb + (size_t)key * 1024 + ks * 32 + quad * 8);
        } else {
          kfv = *(const short8*)(kpb + (size_t)key * 1024 + (ks - 2) * 32 + quad * 8);
          if (key == 0) kfv = (short8)0;  // zero pos-half of k==0 (theta replaces)
        }
#pragma unroll
        for (int mt = 0; mt < 2; ++mt)
          accS[mt][nt] = __builtin_amdgcn_mfma_f32_16x16x32_bf16(qf[mt][ks], kfv, accS[mt][nt], 0, 0, 0);
      }
    }

    // ---- softmax + P store (per-wave LDS, no barrier) ----
#pragma unroll
    for (int mt = 0; mt < 2; ++mt) {
      float s[4][4];
#pragma unroll
      for (int nt = 0; nt < 4; ++nt)
#pragma unroll
        for (int r = 0; r < 4; ++r) s[nt][r] = accS[mt][nt][r] * 0.125f;

      if (kt == 0 || (qt == 0 && wave == 0 && mt == 0)) {
#pragma unroll
        for (int nt = 0; nt < 4; ++nt)
#pragma unroll
          for (int r = 0; r < 4; ++r) {
            int kcol = kt * 64 + nt * 16 + c16;
            int qrow = qt * 128 + wave * 32 + mt * 16 + quad * 4 + r;
            float add = 0.f;
            if (qrow == 0 && kcol == 0) add = tcc;
            else if (qrow == 0) add = tco;
            else if (kcol == 0) add = toc;
            s[nt][r] += add * 0.125f;
          }
      }

      float mx[4];
#pragma unroll
      for (int r = 0; r < 4; ++r)
        mx[r] = fmaxf(fmaxf(s[0][r], s[1][r]), fmaxf(s[2][r], s[3][r]));
#pragma unroll
      for (int d = 1; d < 16; d <<= 1)
#pragma unroll
        for (int r = 0; r < 4; ++r) mx[r] = fmaxf(mx[r], __shfl_xor(mx[r], d, 64));

      float al[4];
#pragma unroll
      for (int r = 0; r < 4; ++r) {
        float mn = fmaxf(mrow[mt][r], mx[r]);
        al[r] = __expf(mrow[mt][r] - mn);
        mrow[mt][r] = mn;
      }

      float rs[4] = {0.f, 0.f, 0.f, 0.f};
#pragma unroll
      for (int nt = 0; nt < 4; ++nt)
#pragma unroll
        for (int r = 0; r < 4; ++r) {
          float p = __expf(s[nt][r] - mrow[mt][r]);
          rs[r] += p;
          int row = quad * 4 + r;
          int ch = nt * 2 + (c16 >> 3);
          Pt[wave][mt * 16 + row][((ch ^ (row & 7)) * 8) + (c16 & 7)] = (short)f2bf(p);
        }
#pragma unroll
      for (int d = 1; d < 16; d <<= 1)
#pragma unroll
        for (int r = 0; r < 4; ++r) rs[r] += __shfl_xor(rs[r], d, 64);
#pragma unroll
      for (int r = 0; r < 4; ++r) lrow[mt][r] = lrow[mt][r] * al[r] + rs[r];
#pragma unroll
      for (int nt = 0; nt < 4; ++nt)
#pragma unroll
        for (int r = 0; r < 4; ++r) accO[mt][nt][r] *= al[r];
    }

    // ---- O += P x V, V-frags straight from global (VcT) ----
#pragma unroll
    for (int ks2 = 0; ks2 < 2; ++ks2) {
      short8 vb[4];
#pragma unroll
      for (int nt = 0; nt < 4; ++nt)
        vb[nt] = *(const short8*)(vtb + (size_t)(nt * 16 + c16) * BS + kt * 64 + ks2 * 32 + quad * 8);
#pragma unroll
      for (int mt = 0; mt < 2; ++mt) {
        short8 pf = *(const short8*)&Pt[wave][mt * 16 + c16][(((ks2 * 4 + quad) ^ (c16 & 7)) & 7) * 8];
#pragma unroll
        for (int nt = 0; nt < 4; ++nt)
          accO[mt][nt] = __builtin_amdgcn_mfma_f32_16x16x32_bf16(pf, vb[nt], accO[mt][nt], 0, 0, 0);
      }
    }
  }

#pragma unroll
  for (int mt = 0; mt < 2; ++mt)
#pragma unroll
    for (int nt = 0; nt < 4; ++nt)
#pragma unroll
      for (int r = 0; r < 4; ++r) {
        int qrow = qt * 128 + wave * 32 + mt * 16 + quad * 4 + r;
        O[((size_t)(b * SEQ + qrow)) * 1024 + h * 64 + nt * 16 + c16] =
            __float2bfloat16(accO[mt][nt][r] / lrow[mt][r]);
      }
}

extern "C" void kernel_launch(void* const* d_in, const int* in_sizes, int n_in,
                              void* d_out, int out_size, void* d_ws, size_t ws_size,
                              hipStream_t stream) {
  const void* q = d_in[0];
  const void* k = d_in[1];
  const void* v = d_in[2];
  const void* Wq = d_in[3];
  const void* bq = d_in[4];
  const void* Wk = d_in[5];
  const void* bk = d_in[6];
  const void* Wv = d_in[7];
  const void* bv = d_in[8];
  const void* Uq = d_in[9];
  const void* buq = d_in[10];
  const void* Uk = d_in[11];
  const void* buk = d_in[12];
  const void* pos = d_in[13];
  const void* th_cc = d_in[14];
  const void* th_co = d_in[15];
  const void* th_oc = d_in[16];
  const void* Wo = d_in[17];
  const void* bo = d_in[18];

  const int M = BS;  // 4096
  const size_t DD = (size_t)D_MODEL * D_MODEL;
  char* wsb = (char*)d_ws;
  int* flag = (int*)wsb;
  bf16* Qc = (bf16*)(wsb + 256);            // 8 MB
  bf16* Kc = Qc + (size_t)M * D_MODEL;      // 8 MB
  bf16* VcT = Kc + (size_t)M * D_MODEL;     // 8 MB, [D_MODEL][M]
  bf16* Qp = VcT + (size_t)M * D_MODEL;     // 2 MB
  bf16* Kp = Qp + (size_t)SEQ * D_MODEL;    // 2 MB
  u16* WT = (u16*)(Kp + (size_t)SEQ * D_MODEL);  // 6 x 2 MB
  bf16* AO = (bf16*)WT;  // aliases WqT..WvT (dead after qkv gemm); WoT untouched

  detect_kernel<<<1, 64, 0, stream>>>((const u16*)q, flag);

  dim3 blk(256);
  transpose_w<<<dim3(32, 32, 6), blk, 0, stream>>>(Wq, Wk, Wv, Uq, Uk, Wo, WT, flag);

  GArgs g1 = {{q, k, v, pos, pos},
              {WT + 0 * DD, WT + 1 * DD, WT + 2 * DD, WT + 3 * DD, WT + 4 * DD},
              {bq, bk, bv, buq, buk},
              {Qc, Kc, VcT, Qp, Kp},
              {M, M, M, SEQ, SEQ},
              {1, 1, 2, 1, 1}};
  gemm_mfma<0><<<dim3(8, 32, 5), blk, 0, stream>>>(g1, flag);

  flash_attn<<<dim3(SEQ / 128, NUM_HEADS, BATCH), blk, 0, stream>>>(
      Qc, Kc, VcT, Qp, Kp, th_cc, th_co, th_oc, AO, flag);

  GArgs g2 = {{AO, AO, AO, AO, AO},
              {WT + 5 * DD, WT + 5 * DD, WT + 5 * DD, WT + 5 * DD, WT + 5 * DD},
              {bo, bo, bo, bo, bo},
              {d_out, d_out, d_out, d_out, d_out},
              {M, M, M, M, M},
              {0, 0, 0, 0, 0}};
  gemm_mfma<1><<<dim3(8, 32, 1), blk, 0, stream>>>(g2, flag);
}